// Round 2
// baseline (396.889 us; speedup 1.0000x reference)
//
#include <hip/hip_runtime.h>
#include <hip/hip_bf16.h>

typedef __attribute__((ext_vector_type(8))) short short8;
typedef __attribute__((ext_vector_type(8))) float f32x8;
typedef __attribute__((ext_vector_type(4))) float f32x4;

#define MFMA16(a, b, c) __builtin_amdgcn_mfma_f32_16x16x32_bf16((a), (b), (c), 0, 0, 0)

// Problem: B=2, S=2048, D=1024, H=16, Dh=64. M = B*S = 4096. All device I/O is FLOAT32.
// ws layout (bf16 elems): Q [32][2048][64] @0, K @4194304, V @8388608, ctx [4096][1024] @12582912

static __device__ __forceinline__ short f2bf(float f) {
    __hip_bfloat16 h = __float2bfloat16(f);
    return *reinterpret_cast<short*>(&h);
}

// load 8 consecutive f32 and convert to a bf16x8 MFMA fragment
static __device__ __forceinline__ short8 ld_cvt8(const float* p) {
    f32x8 v = *reinterpret_cast<const f32x8*>(p);
    short8 r;
#pragma unroll
    for (int j = 0; j < 8; ++j) r[j] = f2bf(v[j]);
    return r;
}

// ---------------- QKV projection GEMM ----------------
// C[m][n] = sum_k x[m][k] * w[n][k]   (w stored [out,in] = B^T form)
// grid: (M/128=32, 3*1024/128=24), 256 threads (4 waves, each 64x64)
__global__ __launch_bounds__(256) void qkv_gemm_kernel(
    const float* __restrict__ x,
    const float* __restrict__ wq,
    const float* __restrict__ wk,
    const float* __restrict__ wv,
    __hip_bfloat16* __restrict__ qkv_out)  // [3][32][2048][64] bf16
{
    const int lane = threadIdx.x & 63;
    const int wid  = threadIdx.x >> 6;
    const int l16  = lane & 15;
    const int lhi  = lane >> 4;
    const int wr = wid >> 1, wc = wid & 1;

    const int mBase = blockIdx.x * 128 + wr * 64;
    const int mat   = blockIdx.y >> 3;                  // 0=q 1=k 2=v
    const int nBase = (blockIdx.y & 7) * 128 + wc * 64; // col within [0,1024)

    const float* w = (mat == 0) ? wq : (mat == 1) ? wk : wv;

    f32x4 acc[4][4] = {};

    for (int kk = 0; kk < 1024; kk += 32) {
        const int ko = kk + lhi * 8;
        short8 a[4], b[4];
#pragma unroll
        for (int i = 0; i < 4; ++i)
            a[i] = ld_cvt8(x + (size_t)(mBase + i * 16 + l16) * 1024 + ko);
#pragma unroll
        for (int j = 0; j < 4; ++j)
            b[j] = ld_cvt8(w + (size_t)(nBase + j * 16 + l16) * 1024 + ko);
#pragma unroll
        for (int i = 0; i < 4; ++i)
#pragma unroll
            for (int j = 0; j < 4; ++j)
                acc[i][j] = MFMA16(a[i], b[j], acc[i][j]);
    }

    // D mapping (m89-verified): col = lane&15, row = (lane>>4)*4 + reg
    __hip_bfloat16* dst = qkv_out + (size_t)mat * 4194304;
#pragma unroll
    for (int i = 0; i < 4; ++i) {
#pragma unroll
        for (int j = 0; j < 4; ++j) {
#pragma unroll
            for (int r = 0; r < 4; ++r) {
                const int mRow = mBase + i * 16 + lhi * 4 + r;
                const int nCol = nBase + j * 16 + l16;
                const int bb = mRow >> 11, s = mRow & 2047;
                const int h = nCol >> 6, d = nCol & 63;
                dst[(((size_t)(bb * 16 + h) * 2048 + s) << 6) + d] =
                    __float2bfloat16(acc[i][j][r]);
            }
        }
    }
}

// ---------------- Flash attention (causal) ----------------
// grid: (S/16=128, B*H=32), 64 threads (1 wave). Each wave: 16 q-rows.
__global__ __launch_bounds__(64) void attn_kernel(
    const __hip_bfloat16* __restrict__ qkv,  // [3][32][2048][64]
    __hip_bfloat16* __restrict__ ctx)        // [4096][1024] = [B*S][H*Dh]
{
    const int lane = threadIdx.x & 63;
    const int l16 = lane & 15;
    const int lhi = lane >> 4;
    const int bh = blockIdx.y;
    const int q0 = blockIdx.x * 16;

    const short* Q = reinterpret_cast<const short*>(qkv) + (size_t)bh * 131072;
    const short* K = Q + 4194304;
    const short* V = Q + 8388608;

    __shared__ __align__(16) short p_lds[16 * 32];

    short8 qf[2];
    qf[0] = *reinterpret_cast<const short8*>(Q + (size_t)(q0 + l16) * 64 + lhi * 8);
    qf[1] = *reinterpret_cast<const short8*>(Q + (size_t)(q0 + l16) * 64 + 32 + lhi * 8);

    f32x4 oacc[4] = {};
    float mrun[4], lrun[4];
#pragma unroll
    for (int r = 0; r < 4; ++r) { mrun[r] = -3.0e38f; lrun[r] = 0.0f; }

    const int nsteps = (q0 >> 5) + 1;  // cover kv <= q0+15
    for (int st = 0; st < nsteps; ++st) {
        const int kv0 = st * 32;
        // ---- scores: Sc[16 q][32 kv] as two 16x16 D tiles ----
        f32x4 sc[2];
#pragma unroll
        for (int nt = 0; nt < 2; ++nt) {
            f32x4 s = {};
#pragma unroll
            for (int ks = 0; ks < 2; ++ks) {
                short8 kb = *reinterpret_cast<const short8*>(
                    K + (size_t)(kv0 + nt * 16 + l16) * 64 + ks * 32 + lhi * 8);
                s = MFMA16(qf[ks], kb, s);
            }
            sc[nt] = s;
        }
        // ---- scale + causal mask + online softmax ----
#pragma unroll
        for (int r = 0; r < 4; ++r) {
            const int qrow = q0 + lhi * 4 + r;
#pragma unroll
            for (int nt = 0; nt < 2; ++nt) {
                const int kv = kv0 + nt * 16 + l16;
                float v = sc[nt][r] * 0.125f;
                if (kv > qrow) v = -3.0e38f;
                sc[nt][r] = v;
            }
            float mx = fmaxf(sc[0][r], sc[1][r]);
            mx = fmaxf(mx, __shfl_xor(mx, 1));
            mx = fmaxf(mx, __shfl_xor(mx, 2));
            mx = fmaxf(mx, __shfl_xor(mx, 4));
            mx = fmaxf(mx, __shfl_xor(mx, 8));

            const float mnew = fmaxf(mrun[r], mx);
            const float alpha = expf(mrun[r] - mnew);
            const float p0 = expf(sc[0][r] - mnew);
            const float p1 = expf(sc[1][r] - mnew);
            float rs = p0 + p1;
            rs += __shfl_xor(rs, 1);
            rs += __shfl_xor(rs, 2);
            rs += __shfl_xor(rs, 4);
            rs += __shfl_xor(rs, 8);
            lrun[r] = lrun[r] * alpha + rs;
            mrun[r] = mnew;
#pragma unroll
            for (int dt = 0; dt < 4; ++dt) oacc[dt][r] *= alpha;

            const int row = lhi * 4 + r;
            p_lds[row * 32 + l16]      = f2bf(p0);
            p_lds[row * 32 + 16 + l16] = f2bf(p1);
        }
        __syncthreads();
        // ---- PV: O[16 q][64 d] += P[16][32] x V[32][64] ----
        short8 pf = *reinterpret_cast<const short8*>(&p_lds[l16 * 32 + lhi * 8]);
#pragma unroll
        for (int dt = 0; dt < 4; ++dt) {
            short8 vb;
#pragma unroll
            for (int j = 0; j < 8; ++j)
                vb[j] = V[(size_t)(kv0 + lhi * 8 + j) * 64 + dt * 16 + l16];
            oacc[dt] = MFMA16(pf, vb, oacc[dt]);
        }
        __syncthreads();
    }

    // ---- epilogue: ctx[b*2048+q][h*64+d] ----
    const int bb = bh >> 4, h = bh & 15;
#pragma unroll
    for (int dt = 0; dt < 4; ++dt) {
#pragma unroll
        for (int r = 0; r < 4; ++r) {
            const int q = q0 + lhi * 4 + r;
            const size_t mRow = (size_t)bb * 2048 + q;
            const int col = h * 64 + dt * 16 + l16;
            ctx[mRow * 1024 + col] = __float2bfloat16(oacc[dt][r] / lrun[r]);
        }
    }
}

// ---------------- Output projection GEMM + bias ----------------
// grid: (32, 8), 256 threads. out (f32) = ctx(bf16) @ wo^T(f32->bf16) + bo(f32)
__global__ __launch_bounds__(256) void out_gemm_kernel(
    const __hip_bfloat16* __restrict__ ctx,
    const float* __restrict__ wo,
    const float* __restrict__ bo,
    float* __restrict__ out)
{
    const int lane = threadIdx.x & 63;
    const int wid  = threadIdx.x >> 6;
    const int l16  = lane & 15;
    const int lhi  = lane >> 4;
    const int wr = wid >> 1, wc = wid & 1;

    const int mBase = blockIdx.x * 128 + wr * 64;
    const int nBase = blockIdx.y * 128 + wc * 64;

    const short* as = reinterpret_cast<const short*>(ctx);

    f32x4 acc[4][4] = {};

    for (int kk = 0; kk < 1024; kk += 32) {
        const int ko = kk + lhi * 8;
        short8 a[4], b[4];
#pragma unroll
        for (int i = 0; i < 4; ++i)
            a[i] = *reinterpret_cast<const short8*>(as + (size_t)(mBase + i * 16 + l16) * 1024 + ko);
#pragma unroll
        for (int j = 0; j < 4; ++j)
            b[j] = ld_cvt8(wo + (size_t)(nBase + j * 16 + l16) * 1024 + ko);
#pragma unroll
        for (int i = 0; i < 4; ++i)
#pragma unroll
            for (int j = 0; j < 4; ++j)
                acc[i][j] = MFMA16(a[i], b[j], acc[i][j]);
    }

#pragma unroll
    for (int i = 0; i < 4; ++i) {
#pragma unroll
        for (int j = 0; j < 4; ++j) {
#pragma unroll
            for (int r = 0; r < 4; ++r) {
                const int mRow = mBase + i * 16 + lhi * 4 + r;
                const int nCol = nBase + j * 16 + l16;
                out[(size_t)mRow * 1024 + nCol] = acc[i][j][r] + bo[nCol];
            }
        }
    }
}

extern "C" void kernel_launch(void* const* d_in, const int* in_sizes, int n_in,
                              void* d_out, int out_size, void* d_ws, size_t ws_size,
                              hipStream_t stream) {
    const float* x  = (const float*)d_in[0];
    const float* wq = (const float*)d_in[1];
    const float* wk = (const float*)d_in[2];
    const float* wv = (const float*)d_in[3];
    const float* wo = (const float*)d_in[4];
    const float* bo = (const float*)d_in[5];

    __hip_bfloat16* ws  = (__hip_bfloat16*)d_ws;   // qkv @0, ctx @12582912
    __hip_bfloat16* ctx = ws + 12582912;
    float* out = (float*)d_out;

    qkv_gemm_kernel<<<dim3(32, 24), 256, 0, stream>>>(x, wq, wk, wv, ws);
    attn_kernel<<<dim3(128, 32), 64, 0, stream>>>(ws, ctx);
    out_gemm_kernel<<<dim3(32, 8), 256, 0, stream>>>(ctx, wo, bo, out);
}

// Round 3
// 344.463 us; speedup vs baseline: 1.1522x; 1.1522x over previous
//
#include <hip/hip_runtime.h>
#include <hip/hip_bf16.h>

typedef __attribute__((ext_vector_type(8))) short short8;
typedef __attribute__((ext_vector_type(4))) short short4_t;
typedef __attribute__((ext_vector_type(8))) float f32x8;
typedef __attribute__((ext_vector_type(4))) float f32x4;

#define MFMA16(a, b, c) __builtin_amdgcn_mfma_f32_16x16x32_bf16((a), (b), (c), 0, 0, 0)

// Problem: B=2, S=2048, D=1024, H=16, Dh=64. M = B*S = 4096. Device I/O is f32.
// ws layout (bf16 elems):
//   Q   [32 bh][2048 s][64 d]  @ 0
//   K   [32 bh][2048 s][64 d]  @ 4194304
//   V^T [32 bh][64 d][2048 s]  @ 8388608
//   ctx [4096 m][1024 n]       @ 12582912

static __device__ __forceinline__ short f2bf(float f) {
    __hip_bfloat16 h = __float2bfloat16(f);
    return *reinterpret_cast<short*>(&h);
}

static __device__ __forceinline__ short8 ld_cvt8(const float* p) {
    f32x8 v = *reinterpret_cast<const f32x8*>(p);
    short8 r;
#pragma unroll
    for (int j = 0; j < 8; ++j) r[j] = f2bf(v[j]);
    return r;
}

// ---------------- QKV projection GEMM ----------------
// grid: (32, 24), 256 threads (4 waves, each 64x64 of the 128x128 tile)
__global__ __launch_bounds__(256) void qkv_gemm_kernel(
    const float* __restrict__ x,
    const float* __restrict__ wq,
    const float* __restrict__ wk,
    const float* __restrict__ wv,
    __hip_bfloat16* __restrict__ qkv_out)
{
    const int lane = threadIdx.x & 63;
    const int wid  = threadIdx.x >> 6;
    const int l16  = lane & 15;
    const int lhi  = lane >> 4;
    const int wr = wid >> 1, wc = wid & 1;

    const int mBase = blockIdx.x * 128 + wr * 64;
    const int mat   = blockIdx.y >> 3;                  // 0=q 1=k 2=v
    const int nBase = (blockIdx.y & 7) * 128 + wc * 64;

    const float* w = (mat == 0) ? wq : (mat == 1) ? wk : wv;

    f32x4 acc[4][4] = {};

    for (int kk = 0; kk < 1024; kk += 32) {
        const int ko = kk + lhi * 8;
        short8 a[4], b[4];
#pragma unroll
        for (int i = 0; i < 4; ++i)
            a[i] = ld_cvt8(x + (size_t)(mBase + i * 16 + l16) * 1024 + ko);
#pragma unroll
        for (int j = 0; j < 4; ++j)
            b[j] = ld_cvt8(w + (size_t)(nBase + j * 16 + l16) * 1024 + ko);
#pragma unroll
        for (int i = 0; i < 4; ++i)
#pragma unroll
            for (int j = 0; j < 4; ++j)
                acc[i][j] = MFMA16(a[i], b[j], acc[i][j]);
    }

    __hip_bfloat16* dst = qkv_out + (size_t)mat * 4194304;
    if (mat < 2) {
        // Q/K row-major per head: [bh][s][64]
#pragma unroll
        for (int i = 0; i < 4; ++i)
#pragma unroll
            for (int j = 0; j < 4; ++j)
#pragma unroll
                for (int r = 0; r < 4; ++r) {
                    const int mRow = mBase + i * 16 + lhi * 4 + r;
                    const int nCol = nBase + j * 16 + l16;
                    const int bb = mRow >> 11, s = mRow & 2047;
                    const int h = nCol >> 6, d = nCol & 63;
                    dst[(((size_t)(bb * 16 + h) * 2048 + s) << 6) + d] =
                        __float2bfloat16(acc[i][j][r]);
                }
    } else {
        // V transposed per head: [bh][d][s]; lane's 4 r-values are 4 consecutive s
#pragma unroll
        for (int i = 0; i < 4; ++i) {
            const int mRow0 = mBase + i * 16 + lhi * 4;
            const int bb = mRow0 >> 11, s0 = mRow0 & 2047;
#pragma unroll
            for (int j = 0; j < 4; ++j) {
                const int nCol = nBase + j * 16 + l16;
                const int h = nCol >> 6, d = nCol & 63;
                short4_t v4;
#pragma unroll
                for (int r = 0; r < 4; ++r) v4[r] = f2bf(acc[i][j][r]);
                *reinterpret_cast<short4_t*>(
                    dst + (((size_t)(bb * 16 + h) * 64 + d) << 11) + s0) = v4;
            }
        }
    }
}

// ---------------- Flash attention (causal) ----------------
// grid: (16, 32), 256 threads = 4 independent waves.
// Wave w of block bx: t = bx*4+w in [0,64); processes q-tiles t and 127-t
// (paired for uniform causal work: ~33 KV-steps of 64 each).
__global__ __launch_bounds__(256) void attn_kernel(
    const __hip_bfloat16* __restrict__ qkv,
    __hip_bfloat16* __restrict__ ctx)
{
    const int lane = threadIdx.x & 63;
    const int wid  = threadIdx.x >> 6;
    const int l16 = lane & 15;
    const int lhi = lane >> 4;
    const int bh = blockIdx.y;
    const int t  = blockIdx.x * 4 + wid;

    const short* Q  = reinterpret_cast<const short*>(qkv) + (size_t)bh * 131072;
    const short* K  = Q + 4194304;
    const short* Vt = Q + 8388608;  // [64 d][2048 s]

    __shared__ __align__(16) short p_lds_all[4][16 * 72];  // per-wave private
    short* p_lds = p_lds_all[wid];

    const int bb = bh >> 4, h = bh & 15;

#pragma unroll 1
    for (int half = 0; half < 2; ++half) {
        const int qt = half ? (127 - t) : t;
        const int q0 = qt * 16;

        short8 qf[2];
        qf[0] = *reinterpret_cast<const short8*>(Q + (size_t)(q0 + l16) * 64 + lhi * 8);
        qf[1] = *reinterpret_cast<const short8*>(Q + (size_t)(q0 + l16) * 64 + 32 + lhi * 8);

        f32x4 oacc[4] = {};
        float mrun[4], lrun[4];
#pragma unroll
        for (int r = 0; r < 4; ++r) { mrun[r] = -3.0e38f; lrun[r] = 0.0f; }

        const int nsteps = (q0 + 16 + 63) >> 6;
#pragma unroll 1
        for (int st = 0; st < nsteps; ++st) {
            const int kv0 = st * 64;
            const bool need_mask = (kv0 + 63) > q0;

            // ---- scores: Sc[16 q][64 kv] as four 16x16 D tiles ----
            f32x4 sc[4];
#pragma unroll
            for (int nt = 0; nt < 4; ++nt) {
                f32x4 s = {};
#pragma unroll
                for (int ks = 0; ks < 2; ++ks) {
                    short8 kb = *reinterpret_cast<const short8*>(
                        K + (size_t)(kv0 + nt * 16 + l16) * 64 + ks * 32 + lhi * 8);
                    s = MFMA16(qf[ks], kb, s);
                }
                sc[nt] = s;
            }

            // ---- scale + causal mask + online softmax ----
#pragma unroll
            for (int r = 0; r < 4; ++r) {
                const int qrow = q0 + lhi * 4 + r;
                float p[4];
#pragma unroll
                for (int nt = 0; nt < 4; ++nt) {
                    float v = sc[nt][r] * 0.125f;
                    if (need_mask && (kv0 + nt * 16 + l16) > qrow) v = -3.0e38f;
                    p[nt] = v;
                }
                float mx = fmaxf(fmaxf(p[0], p[1]), fmaxf(p[2], p[3]));
                mx = fmaxf(mx, __shfl_xor(mx, 1));
                mx = fmaxf(mx, __shfl_xor(mx, 2));
                mx = fmaxf(mx, __shfl_xor(mx, 4));
                mx = fmaxf(mx, __shfl_xor(mx, 8));

                const float mnew = fmaxf(mrun[r], mx);
                const float alpha = __expf(mrun[r] - mnew);
                float rs = 0.0f;
#pragma unroll
                for (int nt = 0; nt < 4; ++nt) {
                    p[nt] = __expf(p[nt] - mnew);
                    rs += p[nt];
                }
                rs += __shfl_xor(rs, 1);
                rs += __shfl_xor(rs, 2);
                rs += __shfl_xor(rs, 4);
                rs += __shfl_xor(rs, 8);
                lrun[r] = lrun[r] * alpha + rs;
                mrun[r] = mnew;
#pragma unroll
                for (int dt = 0; dt < 4; ++dt) oacc[dt][r] *= alpha;

                const int row = lhi * 4 + r;
#pragma unroll
                for (int nt = 0; nt < 4; ++nt)
                    p_lds[row * 72 + nt * 16 + l16] = f2bf(p[nt]);
            }
            asm volatile("s_waitcnt lgkmcnt(0)" ::: "memory");

            // ---- PV: O[16 q][64 d] += P[16][64] x V[64][64] ----
#pragma unroll
            for (int ks = 0; ks < 2; ++ks) {
                short8 pf = *reinterpret_cast<const short8*>(
                    &p_lds[l16 * 72 + ks * 32 + lhi * 8]);
#pragma unroll
                for (int dt = 0; dt < 4; ++dt) {
                    short8 vb = *reinterpret_cast<const short8*>(
                        Vt + (size_t)(dt * 16 + l16) * 2048 + kv0 + ks * 32 + lhi * 8);
                    oacc[dt] = MFMA16(pf, vb, oacc[dt]);
                }
            }
            asm volatile("s_waitcnt lgkmcnt(0)" ::: "memory");
        }

        // ---- epilogue: ctx[bb*2048+q][h*64+d] ----
        float rinv[4];
#pragma unroll
        for (int r = 0; r < 4; ++r) rinv[r] = 1.0f / lrun[r];
#pragma unroll
        for (int dt = 0; dt < 4; ++dt)
#pragma unroll
            for (int r = 0; r < 4; ++r) {
                const int q = q0 + lhi * 4 + r;
                ctx[((size_t)bb * 2048 + q) * 1024 + h * 64 + dt * 16 + l16] =
                    __float2bfloat16(oacc[dt][r] * rinv[r]);
            }
    }
}

// ---------------- Output projection GEMM + bias ----------------
__global__ __launch_bounds__(256) void out_gemm_kernel(
    const __hip_bfloat16* __restrict__ ctx,
    const float* __restrict__ wo,
    const float* __restrict__ bo,
    float* __restrict__ out)
{
    const int lane = threadIdx.x & 63;
    const int wid  = threadIdx.x >> 6;
    const int l16  = lane & 15;
    const int lhi  = lane >> 4;
    const int wr = wid >> 1, wc = wid & 1;

    const int mBase = blockIdx.x * 128 + wr * 64;
    const int nBase = blockIdx.y * 128 + wc * 64;

    const short* as = reinterpret_cast<const short*>(ctx);

    f32x4 acc[4][4] = {};

    for (int kk = 0; kk < 1024; kk += 32) {
        const int ko = kk + lhi * 8;
        short8 a[4], b[4];
#pragma unroll
        for (int i = 0; i < 4; ++i)
            a[i] = *reinterpret_cast<const short8*>(as + (size_t)(mBase + i * 16 + l16) * 1024 + ko);
#pragma unroll
        for (int j = 0; j < 4; ++j)
            b[j] = ld_cvt8(wo + (size_t)(nBase + j * 16 + l16) * 1024 + ko);
#pragma unroll
        for (int i = 0; i < 4; ++i)
#pragma unroll
            for (int j = 0; j < 4; ++j)
                acc[i][j] = MFMA16(a[i], b[j], acc[i][j]);
    }

#pragma unroll
    for (int i = 0; i < 4; ++i)
#pragma unroll
        for (int j = 0; j < 4; ++j)
#pragma unroll
            for (int r = 0; r < 4; ++r) {
                const int mRow = mBase + i * 16 + lhi * 4 + r;
                const int nCol = nBase + j * 16 + l16;
                out[(size_t)mRow * 1024 + nCol] = acc[i][j][r] + bo[nCol];
            }
}

extern "C" void kernel_launch(void* const* d_in, const int* in_sizes, int n_in,
                              void* d_out, int out_size, void* d_ws, size_t ws_size,
                              hipStream_t stream) {
    const float* x  = (const float*)d_in[0];
    const float* wq = (const float*)d_in[1];
    const float* wk = (const float*)d_in[2];
    const float* wv = (const float*)d_in[3];
    const float* wo = (const float*)d_in[4];
    const float* bo = (const float*)d_in[5];

    __hip_bfloat16* ws  = (__hip_bfloat16*)d_ws;
    __hip_bfloat16* ctx = ws + 12582912;
    float* out = (float*)d_out;

    qkv_gemm_kernel<<<dim3(32, 24), 256, 0, stream>>>(x, wq, wk, wv, ws);
    attn_kernel<<<dim3(16, 32), 256, 0, stream>>>(ws, ctx);
    out_gemm_kernel<<<dim3(32, 8), 256, 0, stream>>>(ctx, wo, bo, out);
}

// Round 4
// 196.904 us; speedup vs baseline: 2.0156x; 1.7494x over previous
//
#include <hip/hip_runtime.h>
#include <hip/hip_bf16.h>

typedef __attribute__((ext_vector_type(8))) short short8;
typedef __attribute__((ext_vector_type(4))) short short4_t;
typedef __attribute__((ext_vector_type(8))) float f32x8;
typedef __attribute__((ext_vector_type(4))) float f32x4;

#define MFMA16(a, b, c) __builtin_amdgcn_mfma_f32_16x16x32_bf16((a), (b), (c), 0, 0, 0)

// Problem: B=2, S=2048, D=1024, H=16, Dh=64. M = B*S = 4096. Device I/O f32.
// ws layout (bf16 elem offsets):
//   Q    @ 0         [32 bh][2048 s][64 d]
//   K    @ 4194304
//   V^T  @ 8388608   [32 bh][64 d][2048 s]
//   ctx  @ 12582912  [4096][1024]
//   xbf  @ 16777216  [4096][1024]
//   wqkv @ 20971520  [3072][1024]  (q rows 0-1023, k 1024-2047, v 2048-3071)
//   wobf @ 24117248  [1024][1024]

static __device__ __forceinline__ short f2bf(float f) {
    __hip_bfloat16 h = __float2bfloat16(f);
    return *reinterpret_cast<short*>(&h);
}

static __device__ __forceinline__ void g2l16(const void* g, void* l) {
    __builtin_amdgcn_global_load_lds(
        (const __attribute__((address_space(1))) void*)g,
        (__attribute__((address_space(3))) void*)l,
        16, 0, 0);
}

// ---------------- f32 -> bf16 convert pre-pass ----------------
// 8388608 elems total: x 4194304 | wq 1048576 | wk | wv | wo
__global__ __launch_bounds__(256) void cvt_kernel(
    const float* __restrict__ x,  const float* __restrict__ wq,
    const float* __restrict__ wk, const float* __restrict__ wv,
    const float* __restrict__ wo, __hip_bfloat16* __restrict__ ws)
{
    const size_t e = ((size_t)blockIdx.x * 256 + threadIdx.x) * 8;
    const float* src;
    __hip_bfloat16* dst;
    size_t off;
    if (e < 4194304)      { src = x;  dst = ws + 16777216; off = e; }
    else if (e < 5242880) { src = wq; dst = ws + 20971520; off = e - 4194304; }
    else if (e < 6291456) { src = wk; dst = ws + 20971520 + 1048576; off = e - 5242880; }
    else if (e < 7340032) { src = wv; dst = ws + 20971520 + 2097152; off = e - 6291456; }
    else                  { src = wo; dst = ws + 24117248; off = e - 7340032; }

    f32x8 v = *reinterpret_cast<const f32x8*>(src + off);
    short8 o;
#pragma unroll
    for (int j = 0; j < 8; ++j) o[j] = f2bf(v[j]);
    *reinterpret_cast<short8*>(reinterpret_cast<short*>(dst) + off) = o;
}

// ---------------- QKV projection GEMM (bf16, LDS-staged) ----------------
// 1D grid 768 blocks, 256 threads. XCD-chunked: xcd = bid&7 owns m-blocks [4x,4x+4).
__global__ __launch_bounds__(256) void qkv_gemm_kernel(
    const __hip_bfloat16* __restrict__ xbf_,   // [4096][1024]
    const __hip_bfloat16* __restrict__ wqkv_,  // [3072][1024]
    __hip_bfloat16* __restrict__ qkv_out)
{
    const int bid = blockIdx.x;
    const int xcd = bid & 7, kb = bid >> 3;           // kb in [0,96)
    const int mBlk = xcd * 4 + (kb / 24);             // [0,32)
    const int nBlk = kb % 24;                         // [0,24)

    const int tid  = threadIdx.x;
    const int lane = tid & 63;
    const int wid  = tid >> 6;
    const int l16  = lane & 15;
    const int lhi  = lane >> 4;
    const int wr = wid >> 1, wc = wid & 1;

    const short* A = reinterpret_cast<const short*>(xbf_);
    const short* Bm = reinterpret_cast<const short*>(wqkv_);
    const int r0A = mBlk * 128, r0B = nBlk * 128;

    __shared__ __align__(16) short sA[128 * 64];
    __shared__ __align__(16) short sB[128 * 64];

    f32x4 acc[4][4] = {};

    for (int kk = 0; kk < 1024; kk += 64) {
        // ---- stage A,B tiles (128x64 bf16 each) with XOR-swizzled source ----
#pragma unroll
        for (int it = 0; it < 4; ++it) {
            const int G = it * 256 + tid;
            const int row = G >> 3, gs = G & 7;
            const int gl = gs ^ (row & 7);
            short* lp = sA + (size_t)(it * 256 + wid * 64) * 8;
            g2l16(A + (size_t)(r0A + row) * 1024 + kk + gl * 8, lp);
        }
#pragma unroll
        for (int it = 0; it < 4; ++it) {
            const int G = it * 256 + tid;
            const int row = G >> 3, gs = G & 7;
            const int gl = gs ^ (row & 7);
            short* lp = sB + (size_t)(it * 256 + wid * 64) * 8;
            g2l16(Bm + (size_t)(r0B + row) * 1024 + kk + gl * 8, lp);
        }
        __syncthreads();

#pragma unroll
        for (int ks = 0; ks < 2; ++ks) {
            short8 a[4], b[4];
#pragma unroll
            for (int i = 0; i < 4; ++i) {
                const int row = wr * 64 + i * 16 + l16;
                const int sg = (ks * 4 + lhi) ^ (row & 7);
                a[i] = *reinterpret_cast<const short8*>(&sA[row * 64 + sg * 8]);
            }
#pragma unroll
            for (int j = 0; j < 4; ++j) {
                const int row = wc * 64 + j * 16 + l16;
                const int sg = (ks * 4 + lhi) ^ (row & 7);
                b[j] = *reinterpret_cast<const short8*>(&sB[row * 64 + sg * 8]);
            }
#pragma unroll
            for (int i = 0; i < 4; ++i)
#pragma unroll
                for (int j = 0; j < 4; ++j)
                    acc[i][j] = MFMA16(a[i], b[j], acc[i][j]);
        }
        __syncthreads();
    }

    // ---- epilogue: scatter to per-head Q/K row-major, V transposed ----
    const int nTileBase = nBlk * 128 + wc * 64;
    const int mat = (nTileBase >> 10);                 // 0=q 1=k 2=v (block-uniform)
    __hip_bfloat16* dst = qkv_out + (size_t)mat * 4194304;
    const int mBase = r0A + wr * 64;

    if (mat < 2) {
#pragma unroll
        for (int i = 0; i < 4; ++i)
#pragma unroll
            for (int j = 0; j < 4; ++j)
#pragma unroll
                for (int r = 0; r < 4; ++r) {
                    const int mRow = mBase + i * 16 + lhi * 4 + r;
                    const int nCol = (nTileBase + j * 16 + l16) & 1023;
                    const int bb = mRow >> 11, s = mRow & 2047;
                    const int h = nCol >> 6, d = nCol & 63;
                    dst[(((size_t)(bb * 16 + h) * 2048 + s) << 6) + d] =
                        __float2bfloat16(acc[i][j][r]);
                }
    } else {
#pragma unroll
        for (int i = 0; i < 4; ++i) {
            const int mRow0 = mBase + i * 16 + lhi * 4;
            const int bb = mRow0 >> 11, s0 = mRow0 & 2047;
#pragma unroll
            for (int j = 0; j < 4; ++j) {
                const int nCol = (nTileBase + j * 16 + l16) & 1023;
                const int h = nCol >> 6, d = nCol & 63;
                short4_t v4;
#pragma unroll
                for (int r = 0; r < 4; ++r) v4[r] = f2bf(acc[i][j][r]);
                *reinterpret_cast<short4_t*>(
                    reinterpret_cast<short*>(dst) +
                    (((size_t)(bb * 16 + h) * 64 + d) << 11) + s0) = v4;
            }
        }
    }
}

// ---------------- Flash attention (causal) — unchanged from R3 ----------------
__global__ __launch_bounds__(256) void attn_kernel(
    const __hip_bfloat16* __restrict__ qkv,
    __hip_bfloat16* __restrict__ ctx)
{
    const int lane = threadIdx.x & 63;
    const int wid  = threadIdx.x >> 6;
    const int l16 = lane & 15;
    const int lhi = lane >> 4;
    const int bh = blockIdx.y;
    const int t  = blockIdx.x * 4 + wid;

    const short* Q  = reinterpret_cast<const short*>(qkv) + (size_t)bh * 131072;
    const short* K  = Q + 4194304;
    const short* Vt = Q + 8388608;

    __shared__ __align__(16) short p_lds_all[4][16 * 72];
    short* p_lds = p_lds_all[wid];

    const int bb = bh >> 4, h = bh & 15;

#pragma unroll 1
    for (int half = 0; half < 2; ++half) {
        const int qt = half ? (127 - t) : t;
        const int q0 = qt * 16;

        short8 qf[2];
        qf[0] = *reinterpret_cast<const short8*>(Q + (size_t)(q0 + l16) * 64 + lhi * 8);
        qf[1] = *reinterpret_cast<const short8*>(Q + (size_t)(q0 + l16) * 64 + 32 + lhi * 8);

        f32x4 oacc[4] = {};
        float mrun[4], lrun[4];
#pragma unroll
        for (int r = 0; r < 4; ++r) { mrun[r] = -3.0e38f; lrun[r] = 0.0f; }

        const int nsteps = (q0 + 16 + 63) >> 6;
#pragma unroll 1
        for (int st = 0; st < nsteps; ++st) {
            const int kv0 = st * 64;
            const bool need_mask = (kv0 + 63) > q0;

            f32x4 sc[4];
#pragma unroll
            for (int nt = 0; nt < 4; ++nt) {
                f32x4 s = {};
#pragma unroll
                for (int ks = 0; ks < 2; ++ks) {
                    short8 kb = *reinterpret_cast<const short8*>(
                        K + (size_t)(kv0 + nt * 16 + l16) * 64 + ks * 32 + lhi * 8);
                    s = MFMA16(qf[ks], kb, s);
                }
                sc[nt] = s;
            }

#pragma unroll
            for (int r = 0; r < 4; ++r) {
                const int qrow = q0 + lhi * 4 + r;
                float p[4];
#pragma unroll
                for (int nt = 0; nt < 4; ++nt) {
                    float v = sc[nt][r] * 0.125f;
                    if (need_mask && (kv0 + nt * 16 + l16) > qrow) v = -3.0e38f;
                    p[nt] = v;
                }
                float mx = fmaxf(fmaxf(p[0], p[1]), fmaxf(p[2], p[3]));
                mx = fmaxf(mx, __shfl_xor(mx, 1));
                mx = fmaxf(mx, __shfl_xor(mx, 2));
                mx = fmaxf(mx, __shfl_xor(mx, 4));
                mx = fmaxf(mx, __shfl_xor(mx, 8));

                const float mnew = fmaxf(mrun[r], mx);
                const float alpha = __expf(mrun[r] - mnew);
                float rs = 0.0f;
#pragma unroll
                for (int nt = 0; nt < 4; ++nt) {
                    p[nt] = __expf(p[nt] - mnew);
                    rs += p[nt];
                }
                rs += __shfl_xor(rs, 1);
                rs += __shfl_xor(rs, 2);
                rs += __shfl_xor(rs, 4);
                rs += __shfl_xor(rs, 8);
                lrun[r] = lrun[r] * alpha + rs;
                mrun[r] = mnew;
#pragma unroll
                for (int dt = 0; dt < 4; ++dt) oacc[dt][r] *= alpha;

                const int row = lhi * 4 + r;
#pragma unroll
                for (int nt = 0; nt < 4; ++nt)
                    p_lds[row * 72 + nt * 16 + l16] = f2bf(p[nt]);
            }
            asm volatile("s_waitcnt lgkmcnt(0)" ::: "memory");

#pragma unroll
            for (int ks = 0; ks < 2; ++ks) {
                short8 pf = *reinterpret_cast<const short8*>(
                    &p_lds[l16 * 72 + ks * 32 + lhi * 8]);
#pragma unroll
                for (int dt = 0; dt < 4; ++dt) {
                    short8 vb = *reinterpret_cast<const short8*>(
                        Vt + (size_t)(dt * 16 + l16) * 2048 + kv0 + ks * 32 + lhi * 8);
                    oacc[dt] = MFMA16(pf, vb, oacc[dt]);
                }
            }
            asm volatile("s_waitcnt lgkmcnt(0)" ::: "memory");
        }

        float rinv[4];
#pragma unroll
        for (int r = 0; r < 4; ++r) rinv[r] = 1.0f / lrun[r];
#pragma unroll
        for (int dt = 0; dt < 4; ++dt)
#pragma unroll
            for (int r = 0; r < 4; ++r) {
                const int q = q0 + lhi * 4 + r;
                ctx[((size_t)bb * 2048 + q) * 1024 + h * 64 + dt * 16 + l16] =
                    __float2bfloat16(oacc[dt][r] * rinv[r]);
            }
    }
}

// ---------------- Output projection GEMM + bias (bf16, LDS-staged) ----------------
// 1D grid 256 blocks. xcd-chunked like qkv.
__global__ __launch_bounds__(256) void out_gemm_kernel(
    const __hip_bfloat16* __restrict__ ctx,   // [4096][1024]
    const __hip_bfloat16* __restrict__ wobf,  // [1024][1024]
    const float* __restrict__ bo,
    float* __restrict__ out)
{
    const int bid = blockIdx.x;
    const int xcd = bid & 7, kb = bid >> 3;           // kb in [0,32)
    const int mBlk = xcd * 4 + (kb >> 3);
    const int nBlk = kb & 7;

    const int tid  = threadIdx.x;
    const int lane = tid & 63;
    const int wid  = tid >> 6;
    const int l16  = lane & 15;
    const int lhi  = lane >> 4;
    const int wr = wid >> 1, wc = wid & 1;

    const short* A = reinterpret_cast<const short*>(ctx);
    const short* Bm = reinterpret_cast<const short*>(wobf);
    const int r0A = mBlk * 128, r0B = nBlk * 128;

    __shared__ __align__(16) short sA[128 * 64];
    __shared__ __align__(16) short sB[128 * 64];

    f32x4 acc[4][4] = {};

    for (int kk = 0; kk < 1024; kk += 64) {
#pragma unroll
        for (int it = 0; it < 4; ++it) {
            const int G = it * 256 + tid;
            const int row = G >> 3, gs = G & 7;
            const int gl = gs ^ (row & 7);
            short* lp = sA + (size_t)(it * 256 + wid * 64) * 8;
            g2l16(A + (size_t)(r0A + row) * 1024 + kk + gl * 8, lp);
        }
#pragma unroll
        for (int it = 0; it < 4; ++it) {
            const int G = it * 256 + tid;
            const int row = G >> 3, gs = G & 7;
            const int gl = gs ^ (row & 7);
            short* lp = sB + (size_t)(it * 256 + wid * 64) * 8;
            g2l16(Bm + (size_t)(r0B + row) * 1024 + kk + gl * 8, lp);
        }
        __syncthreads();

#pragma unroll
        for (int ks = 0; ks < 2; ++ks) {
            short8 a[4], b[4];
#pragma unroll
            for (int i = 0; i < 4; ++i) {
                const int row = wr * 64 + i * 16 + l16;
                const int sg = (ks * 4 + lhi) ^ (row & 7);
                a[i] = *reinterpret_cast<const short8*>(&sA[row * 64 + sg * 8]);
            }
#pragma unroll
            for (int j = 0; j < 4; ++j) {
                const int row = wc * 64 + j * 16 + l16;
                const int sg = (ks * 4 + lhi) ^ (row & 7);
                b[j] = *reinterpret_cast<const short8*>(&sB[row * 64 + sg * 8]);
            }
#pragma unroll
            for (int i = 0; i < 4; ++i)
#pragma unroll
                for (int j = 0; j < 4; ++j)
                    acc[i][j] = MFMA16(a[i], b[j], acc[i][j]);
        }
        __syncthreads();
    }

    const int mBase = r0A + wr * 64;
    const int nBase = r0B + wc * 64;
#pragma unroll
    for (int i = 0; i < 4; ++i)
#pragma unroll
        for (int j = 0; j < 4; ++j)
#pragma unroll
            for (int r = 0; r < 4; ++r) {
                const int mRow = mBase + i * 16 + lhi * 4 + r;
                const int nCol = nBase + j * 16 + l16;
                out[(size_t)mRow * 1024 + nCol] = acc[i][j][r] + bo[nCol];
            }
}

extern "C" void kernel_launch(void* const* d_in, const int* in_sizes, int n_in,
                              void* d_out, int out_size, void* d_ws, size_t ws_size,
                              hipStream_t stream) {
    const float* x  = (const float*)d_in[0];
    const float* wq = (const float*)d_in[1];
    const float* wk = (const float*)d_in[2];
    const float* wv = (const float*)d_in[3];
    const float* wo = (const float*)d_in[4];
    const float* bo = (const float*)d_in[5];

    __hip_bfloat16* ws = (__hip_bfloat16*)d_ws;
    __hip_bfloat16* ctx  = ws + 12582912;
    __hip_bfloat16* xbf  = ws + 16777216;
    __hip_bfloat16* wqkv = ws + 20971520;
    __hip_bfloat16* wobf = ws + 24117248;
    float* out = (float*)d_out;

    cvt_kernel<<<4096, 256, 0, stream>>>(x, wq, wk, wv, wo, ws);
    qkv_gemm_kernel<<<768, 256, 0, stream>>>(xbf, wqkv, ws);
    attn_kernel<<<dim3(16, 32), 256, 0, stream>>>(ws, ctx);
    out_gemm_kernel<<<256, 256, 0, stream>>>(ctx, wobf, bo, out);
}